// Round 2
// baseline (626.892 us; speedup 1.0000x reference)
//
#include <hip/hip_runtime.h>

// BiPixelMambaLayer: D_MODEL=256, D_INNER=512, D_STATE=16, D_CONV=4, DT_RANK=16, PATCH=64
// x: (2, 256, 4096) fp32.  Mamba batch B'=128 (= 2*64), seq NPT=64, channels along patch axis.
// xd[b*64+p, c, n] = x[b, c, n*64+p]
//
// Workspace layout (floats), total ~85 MB (assumes ws_size >= 90 MB):
//   XZ  [128][64][1024]  = 8388608   (xz, position-major: [b'][l][e])
//   XC  [128][64][512]   = 4194304   (conv+silu output, scan-order per branch; reused fwd/bwd)
//   DL  [128][64][512]   = 4194304   (delta, softplus'd; reused)
//   BCB [128][64][32]    = 262144    (B then C per position; reused)
//   YA  [128][64][512]   = 4194304   (gated y accumulator: fwd '=' then bwd '+=')

#define OFF_XZ 0
#define OFF_XC 8388608
#define OFF_DL 12582912
#define OFF_BC 16777216
#define OFF_YA 17039360

__device__ __forceinline__ float siluf(float v) {
    return v / (1.f + __expf(-v));
}
__device__ __forceinline__ float softplusf(float v) {
    return (v > 20.f) ? v : log1pf(__expf(v));
}

// ---------------- K1: LayerNorm + in_proj (256 -> 1024), 16 positions per block ----------
__global__ __launch_bounds__(256) void k_ln_inproj(
    const float* __restrict__ x, const float* __restrict__ g,
    const float* __restrict__ bt, const float* __restrict__ W,
    float* __restrict__ xz)
{
    __shared__ float sx[16][256];
    const int p0  = blockIdx.x * 16;          // flat position = b'*64 + l
    const int tid = threadIdx.x;
    const int wave = tid >> 6, lane = tid & 63;

    // Phase 1: LN. Each of 4 waves handles 4 positions; lane holds 4 channels.
    for (int i = 0; i < 4; ++i) {
        int pos = p0 + wave * 4 + i;
        int bp = pos >> 6, l = pos & 63;
        int b = bp >> 6, pp = bp & 63;
        const float* xb = x + ((size_t)b * 256) * 4096 + (size_t)l * 64 + pp;
        float v0 = xb[(size_t)(lane * 4 + 0) * 4096];
        float v1 = xb[(size_t)(lane * 4 + 1) * 4096];
        float v2 = xb[(size_t)(lane * 4 + 2) * 4096];
        float v3 = xb[(size_t)(lane * 4 + 3) * 4096];
        float s = v0 + v1 + v2 + v3;
        #pragma unroll
        for (int o = 32; o; o >>= 1) s += __shfl_xor(s, o);
        float mu = s * (1.f / 256.f);
        float q0 = v0 - mu, q1 = v1 - mu, q2 = v2 - mu, q3 = v3 - mu;
        float q = q0 * q0 + q1 * q1 + q2 * q2 + q3 * q3;
        #pragma unroll
        for (int o = 32; o; o >>= 1) q += __shfl_xor(q, o);
        float rs = rsqrtf(q * (1.f / 256.f) + 1e-5f);
        int c = lane * 4;
        int pi = wave * 4 + i;
        sx[pi][c + 0] = q0 * rs * g[c + 0] + bt[c + 0];
        sx[pi][c + 1] = q1 * rs * g[c + 1] + bt[c + 1];
        sx[pi][c + 2] = q2 * rs * g[c + 2] + bt[c + 2];
        sx[pi][c + 3] = q3 * rs * g[c + 3] + bt[c + 3];
    }
    __syncthreads();

    // Phase 2: [16 x 256] @ W^T (W is [1024][256]) -> [16 x 1024]
    float acc[4][16];
    #pragma unroll
    for (int j = 0; j < 4; ++j)
        #pragma unroll
        for (int p = 0; p < 16; ++p) acc[j][p] = 0.f;

    for (int c4 = 0; c4 < 64; ++c4) {
        float4 w4[4];
        #pragma unroll
        for (int j = 0; j < 4; ++j)
            w4[j] = *(const float4*)&W[(size_t)(j * 256 + tid) * 256 + c4 * 4];
        #pragma unroll
        for (int p = 0; p < 16; ++p) {
            float4 xp = *(const float4*)&sx[p][c4 * 4];
            #pragma unroll
            for (int j = 0; j < 4; ++j) {
                acc[j][p] = fmaf(w4[j].x, xp.x, acc[j][p]);
                acc[j][p] = fmaf(w4[j].y, xp.y, acc[j][p]);
                acc[j][p] = fmaf(w4[j].z, xp.z, acc[j][p]);
                acc[j][p] = fmaf(w4[j].w, xp.w, acc[j][p]);
            }
        }
    }
    #pragma unroll
    for (int j = 0; j < 4; ++j)
        #pragma unroll
        for (int p = 0; p < 16; ++p)
            xz[(size_t)(p0 + p) * 1024 + j * 256 + tid] = acc[j][p];
}

// ---------------- K2: causal depthwise conv(4) + SiLU (scan-order output) ----------------
__global__ __launch_bounds__(512) void k_conv(
    const float* __restrict__ xz, const float* __restrict__ cw,
    const float* __restrict__ cb, float* __restrict__ xc, int rev)
{
    const int bp = blockIdx.x;
    const int d  = threadIdx.x;
    const float w0 = cw[d * 4 + 0], w1 = cw[d * 4 + 1], w2 = cw[d * 4 + 2], w3 = cw[d * 4 + 3];
    const float bb = cb[d];
    float p1 = 0.f, p2 = 0.f, p3 = 0.f;
    for (int i = 0; i < 64; ++i) {
        int l = rev ? 63 - i : i;
        float cur = xz[((size_t)bp * 64 + l) * 1024 + d];
        float y = w3 * cur + w2 * p1 + w1 * p2 + w0 * p3 + bb;
        xc[((size_t)bp * 64 + i) * 512 + d] = siluf(y);
        p3 = p2; p2 = p1; p1 = cur;
    }
}

// ---------------- K3: x_proj (512 -> 48) + dt_proj (16 -> 512) + softplus ----------------
__global__ __launch_bounds__(256) void k_xdt(
    const float* __restrict__ xc, const float* __restrict__ W6,
    const float* __restrict__ dtw, const float* __restrict__ dtb,
    float* __restrict__ delta, float* __restrict__ bcb)
{
    __shared__ float sx2[16][512];
    __shared__ float sdbl[16][48];
    const int p0  = blockIdx.x * 16;
    const int tid = threadIdx.x;

    // load 16x512 contiguous tile
    {
        const float4* src = (const float4*)(xc + (size_t)p0 * 512);
        float4* dst = (float4*)&sx2[0][0];
        #pragma unroll
        for (int q = 0; q < 8; ++q) dst[q * 256 + tid] = src[q * 256 + tid];
    }
    __syncthreads();

    // x_proj: 16 pos x 48 outputs = 768 = 3*256
    #pragma unroll
    for (int k = 0; k < 3; ++k) {
        int o = k * 256 + tid;
        int p = o / 48, e = o - p * 48;
        const float4* wr = (const float4*)(W6 + (size_t)e * 512);
        float a = 0.f;
        for (int c4 = 0; c4 < 128; ++c4) {
            float4 w = wr[c4];
            float4 xv = *(const float4*)&sx2[p][c4 * 4];
            a = fmaf(w.x, xv.x, a); a = fmaf(w.y, xv.y, a);
            a = fmaf(w.z, xv.z, a); a = fmaf(w.w, xv.w, a);
        }
        sdbl[p][e] = a;
    }
    __syncthreads();

    // dt_proj + softplus: 16 pos x 512 d = 8192 = 32*256
    #pragma unroll
    for (int k = 0; k < 32; ++k) {
        int o = k * 256 + tid;
        int p = o >> 9, d = o & 511;
        const float4* wr = (const float4*)(dtw + (size_t)d * 16);
        float a = dtb[d];
        #pragma unroll
        for (int r4 = 0; r4 < 4; ++r4) {
            float4 w = wr[r4];
            float4 xv = *(const float4*)&sdbl[p][r4 * 4];
            a = fmaf(w.x, xv.x, a); a = fmaf(w.y, xv.y, a);
            a = fmaf(w.z, xv.z, a); a = fmaf(w.w, xv.w, a);
        }
        delta[(size_t)(p0 + p) * 512 + d] = softplusf(a);
    }
    // B and C: 16 pos x 32 = 512 = 2*256
    #pragma unroll
    for (int k = 0; k < 2; ++k) {
        int o = k * 256 + tid;
        int p = o >> 5, n = o & 31;
        bcb[(size_t)(p0 + p) * 32 + n] = sdbl[p][16 + n];
    }
}

// ---------------- K4: selective scan + D*u + SiLU(z) gate ----------------
__global__ __launch_bounds__(256) void k_scan(
    const float* __restrict__ delta, const float* __restrict__ u_,
    const float* __restrict__ bc_, const float* __restrict__ xz,
    const float* __restrict__ A_log, const float* __restrict__ Dp,
    float* __restrict__ yacc, int rev)
{
    const int bid = blockIdx.x;
    const int bp  = bid >> 1;
    const int d   = ((bid & 1) << 8) + threadIdx.x;

    float a[16];
    #pragma unroll
    for (int n = 0; n < 16; ++n) a[n] = -__expf(A_log[(size_t)d * 16 + n]);
    const float Dd = Dp[d];

    float h[16];
    #pragma unroll
    for (int n = 0; n < 16; ++n) h[n] = 0.f;

    for (int l = 0; l < 64; ++l) {
        size_t base = (size_t)bp * 64 + l;
        float dl = delta[base * 512 + d];
        float uu = u_[base * 512 + d];
        float du = dl * uu;
        const float4* bc = (const float4*)(bc_ + base * 32);
        float y = 0.f;
        #pragma unroll
        for (int n4 = 0; n4 < 4; ++n4) {
            float4 Bv = bc[n4];
            float4 Cv = bc[4 + n4];
            int n = n4 * 4;
            h[n + 0] = fmaf(__expf(dl * a[n + 0]), h[n + 0], du * Bv.x); y = fmaf(h[n + 0], Cv.x, y);
            h[n + 1] = fmaf(__expf(dl * a[n + 1]), h[n + 1], du * Bv.y); y = fmaf(h[n + 1], Cv.y, y);
            h[n + 2] = fmaf(__expf(dl * a[n + 2]), h[n + 2], du * Bv.z); y = fmaf(h[n + 2], Cv.z, y);
            h[n + 3] = fmaf(__expf(dl * a[n + 3]), h[n + 3], du * Bv.w); y = fmaf(h[n + 3], Cv.w, y);
        }
        y = fmaf(Dd, uu, y);
        int lo = rev ? 63 - l : l;
        float zv = xz[((size_t)bp * 64 + lo) * 1024 + 512 + d];
        float out = y * siluf(zv);
        float* dst = yacc + ((size_t)bp * 64 + lo) * 512 + d;
        if (rev) *dst += out;
        else     *dst  = out;
    }
}

// ---------------- K5: out_proj (512 -> 256) + un-shuffle + residual ----------------
// Block handles 16 positions strided by 64: {(bp0+i)*64 + l}, so output writes are float4.
__global__ __launch_bounds__(256) void k_outproj(
    const float* __restrict__ yacc, const float* __restrict__ Wout,
    const float* __restrict__ x, float* __restrict__ out)
{
    __shared__ float sy[16][512];
    const int blk = blockIdx.x;           // g*64 + l
    const int g = blk >> 6, l = blk & 63;
    const int bp0 = g * 16;
    const int b = bp0 >> 6, pp0 = bp0 & 63;
    const int tid = threadIdx.x;

    #pragma unroll
    for (int q = 0; q < 8; ++q) {
        int fq = q * 256 + tid;           // float4 index over 16x512 tile
        int i = fq >> 7, d4 = fq & 127;
        ((float4*)&sy[i][0])[d4] =
            *(const float4*)(yacc + ((size_t)(bp0 + i) * 64 + l) * 512 + d4 * 4);
    }
    __syncthreads();

    const int c = tid;
    float acc[16];
    #pragma unroll
    for (int i = 0; i < 16; ++i) acc[i] = 0.f;
    const float4* wr = (const float4*)(Wout + (size_t)c * 512);
    for (int d4 = 0; d4 < 128; ++d4) {
        float4 w = wr[d4];
        #pragma unroll
        for (int i = 0; i < 16; ++i) {
            float4 xv = *(const float4*)&sy[i][d4 * 4];
            acc[i] = fmaf(w.x, xv.x, acc[i]);
            acc[i] = fmaf(w.y, xv.y, acc[i]);
            acc[i] = fmaf(w.z, xv.z, acc[i]);
            acc[i] = fmaf(w.w, xv.w, acc[i]);
        }
    }
    #pragma unroll
    for (int i4 = 0; i4 < 4; ++i4) {
        size_t idx = ((size_t)(b * 256 + c)) * 4096 + (size_t)l * 64 + pp0 + i4 * 4;
        float4 xr = *(const float4*)(x + idx);
        float4 v;
        v.x = acc[i4 * 4 + 0] + xr.x;
        v.y = acc[i4 * 4 + 1] + xr.y;
        v.z = acc[i4 * 4 + 2] + xr.z;
        v.w = acc[i4 * 4 + 3] + xr.w;
        *(float4*)(out + idx) = v;
    }
}

extern "C" void kernel_launch(void* const* d_in, const int* in_sizes, int n_in,
                              void* d_out, int out_size, void* d_ws, size_t ws_size,
                              hipStream_t stream) {
    const float* x        = (const float*)d_in[0];
    const float* ln_g     = (const float*)d_in[1];
    const float* ln_b     = (const float*)d_in[2];
    const float* in_w     = (const float*)d_in[3];
    const float* conv_w   = (const float*)d_in[4];
    const float* conv_b   = (const float*)d_in[5];
    const float* xproj_w  = (const float*)d_in[6];
    const float* dtp_w    = (const float*)d_in[7];
    const float* dtp_b    = (const float*)d_in[8];
    const float* A_log    = (const float*)d_in[9];
    const float* D_f      = (const float*)d_in[10];
    const float* conv_w_b = (const float*)d_in[11];
    const float* conv_b_b = (const float*)d_in[12];
    const float* xproj_wb = (const float*)d_in[13];
    const float* dtp_w_b  = (const float*)d_in[14];
    const float* dtp_b_b  = (const float*)d_in[15];
    const float* A_b_log  = (const float*)d_in[16];
    const float* D_b      = (const float*)d_in[17];
    const float* out_w    = (const float*)d_in[18];
    float* out = (float*)d_out;

    float* ws  = (float*)d_ws;
    float* xz  = ws + OFF_XZ;
    float* xc  = ws + OFF_XC;
    float* dl  = ws + OFF_DL;
    float* bc  = ws + OFF_BC;
    float* ya  = ws + OFF_YA;

    // 1. LN + in_proj
    k_ln_inproj<<<512, 256, 0, stream>>>(x, ln_g, ln_b, in_w, xz);
    // forward branch
    k_conv<<<128, 512, 0, stream>>>(xz, conv_w, conv_b, xc, 0);
    k_xdt<<<512, 256, 0, stream>>>(xc, xproj_w, dtp_w, dtp_b, dl, bc);
    k_scan<<<256, 256, 0, stream>>>(dl, xc, bc, xz, A_log, D_f, ya, 0);
    // backward branch (reversed scan order, buffers reused)
    k_conv<<<128, 512, 0, stream>>>(xz, conv_w_b, conv_b_b, xc, 1);
    k_xdt<<<512, 256, 0, stream>>>(xc, xproj_wb, dtp_w_b, dtp_b_b, dl, bc);
    k_scan<<<256, 256, 0, stream>>>(dl, xc, bc, xz, A_b_log, D_b, ya, 1);
    // out_proj + scatter + residual
    k_outproj<<<512, 256, 0, stream>>>(ya, out_w, x, out);
}

// Round 5
// 546.692 us; speedup vs baseline: 1.1467x; 1.1467x over previous
//
#include <hip/hip_runtime.h>

// BiPixelMambaLayer: D_MODEL=256, D_INNER=512, D_STATE=16, D_CONV=4, DT_RANK=16, PATCH=64
// x: (2, 256, 4096) fp32.  Mamba batch B'=128 (= 2*64), seq NPT=64, channels along patch axis.
// xd[b*64+p, c, n] = x[b, c, n*64+p]
//
// Workspace layout (floats), total ~85 MB:
//   XZ  [128][64][1024]  = 8388608   (xz, position-major: [b'][l][e])
//   XC  [128][64][512]   = 4194304   (conv+silu output, scan-order per branch; reused fwd/bwd)
//   DL  [128][64][512]   = 4194304   (delta, softplus'd; reused)
//   BCB [128][64][32]    = 262144    (B then C per position; reused)  -- also holds W_bf16 during K1
//   YA  [128][64][512]   = 4194304   (gated y accumulator: fwd '=' then bwd '+=')

#define OFF_XZ 0
#define OFF_XC 8388608
#define OFF_DL 12582912
#define OFF_BC 16777216
#define OFF_YA 17039360

typedef __attribute__((ext_vector_type(8))) short short8;
typedef __attribute__((ext_vector_type(4))) float f32x4;

__device__ __forceinline__ float siluf(float v) {
    return v / (1.f + __expf(-v));
}
__device__ __forceinline__ float softplusf(float v) {
    return (v > 20.f) ? v : log1pf(__expf(v));
}
__device__ __forceinline__ unsigned short f2bf(float f) {
    union { float f; unsigned int u; } v; v.f = f;
    unsigned int u = v.u;
    return (unsigned short)((u + 0x7FFFu + ((u >> 16) & 1u)) >> 16);
}

// ---------------- K0: convert in_proj W (1024x256 fp32) to bf16 ----------------
__global__ __launch_bounds__(256) void k_cvt_w(
    const float* __restrict__ W, unsigned short* __restrict__ Wb)
{
    int i = (blockIdx.x * 256 + threadIdx.x) * 4;   // 262144 elems / 4
    float4 v = *(const float4*)(W + i);
    ushort4 o;
    o.x = f2bf(v.x); o.y = f2bf(v.y); o.z = f2bf(v.z); o.w = f2bf(v.w);
    *(ushort4*)(Wb + i) = o;
}

// ---------------- K1: LayerNorm + in_proj (256 -> 1024) via bf16 MFMA ----------------
// Grid: 512 = 128 pos-groups (64 pos each, == one bp row, l=0..63) x 4 out-groups (256 cols).
// Block: 256 thr = 4 waves. Wave computes 64 pos x 64 cols as 4x4 tiles of 16x16, K-loop 8x32.
__global__ __launch_bounds__(256) void k_ln_inproj_mfma(
    const float* __restrict__ x, const float* __restrict__ g,
    const float* __restrict__ bt, const unsigned short* __restrict__ Wb,
    float* __restrict__ xz)
{
    __shared__ unsigned short sxb[64 * 256];   // 32 KB, bf16, XOR-swizzled rows of 512B
    const int bid = blockIdx.x;
    const int pg = bid >> 2, og = bid & 3;
    const int p0 = pg * 64;                    // pos-group base; bp = pg, l = row m
    const int tid = threadIdx.x;
    const int wave = tid >> 6, lane = tid & 63;
    const int b = pg >> 6, pp = pg & 63;
    const float* xb = x + ((size_t)b * 256) * 4096 + pp;

    // ---- Phase 1: LN for 64 positions (wave w: rows w*16..w*16+15; lane: 4 channels) ----
    const int c = lane * 4;
    const float g0 = g[c + 0], g1 = g[c + 1], g2 = g[c + 2], g3 = g[c + 3];
    const float b0 = bt[c + 0], b1 = bt[c + 1], b2 = bt[c + 2], b3 = bt[c + 3];
    for (int i = 0; i < 16; ++i) {
        int m = wave * 16 + i;                 // row in tile == l
        const float* xr = xb + m * 64;
        float v0 = xr[(size_t)(c + 0) * 4096];
        float v1 = xr[(size_t)(c + 1) * 4096];
        float v2 = xr[(size_t)(c + 2) * 4096];
        float v3 = xr[(size_t)(c + 3) * 4096];
        float s = v0 + v1 + v2 + v3;
        #pragma unroll
        for (int o = 32; o; o >>= 1) s += __shfl_xor(s, o);
        float mu = s * (1.f / 256.f);
        float q0 = v0 - mu, q1 = v1 - mu, q2 = v2 - mu, q3 = v3 - mu;
        float q = q0 * q0 + q1 * q1 + q2 * q2 + q3 * q3;
        #pragma unroll
        for (int o = 32; o; o >>= 1) q += __shfl_xor(q, o);
        float rs = rsqrtf(q * (1.f / 256.f) + 1e-5f);
        ushort4 pk;
        pk.x = f2bf(q0 * rs * g0 + b0);
        pk.y = f2bf(q1 * rs * g1 + b1);
        pk.z = f2bf(q2 * rs * g2 + b2);
        pk.w = f2bf(q3 * rs * g3 + b3);
        int byte = m * 512 + lane * 8;
        byte ^= (m & 7) << 4;                  // T2 swizzle: spread 512B-stride rows over banks
        *(ushort4*)((char*)sxb + byte) = pk;
    }
    __syncthreads();

    // ---- Phase 2: MFMA GEMM. acc[mi][ni] over 4x4 tiles of 16x16, K = 256 in 8 steps ----
    const int nbase = og * 256 + wave * 64;    // wave's first output column
    const int l15 = lane & 15, lg = lane >> 4; // fragment row / k-group
    f32x4 acc[4][4];
    #pragma unroll
    for (int mi = 0; mi < 4; ++mi)
        #pragma unroll
        for (int ni = 0; ni < 4; ++ni) acc[mi][ni] = (f32x4){0.f, 0.f, 0.f, 0.f};

    // per-lane W row pointers (W stored [N][K] row-major = B^T input pattern)
    const unsigned short* wrow[4];
    #pragma unroll
    for (int ni = 0; ni < 4; ++ni)
        wrow[ni] = Wb + (size_t)(nbase + ni * 16 + l15) * 256 + lg * 8;

    #pragma unroll 2
    for (int k0 = 0; k0 < 256; k0 += 32) {
        short8 a[4], bfr[4];
        #pragma unroll
        for (int mi = 0; mi < 4; ++mi) {
            int row = mi * 16 + l15;
            int byte = row * 512 + k0 * 2 + lg * 16;
            byte ^= (row & 7) << 4;
            a[mi] = *(const short8*)((const char*)sxb + byte);
        }
        #pragma unroll
        for (int ni = 0; ni < 4; ++ni)
            bfr[ni] = *(const short8*)(wrow[ni] + k0);
        #pragma unroll
        for (int mi = 0; mi < 4; ++mi)
            #pragma unroll
            for (int ni = 0; ni < 4; ++ni)
                acc[mi][ni] = __builtin_amdgcn_mfma_f32_16x16x32_bf16(
                    a[mi], bfr[ni], acc[mi][ni], 0, 0, 0);
    }

    // ---- Epilogue: D[m][n], m = mi*16 + lg*4 + r, n = nbase + ni*16 + l15 ----
    #pragma unroll
    for (int mi = 0; mi < 4; ++mi)
        #pragma unroll
        for (int ni = 0; ni < 4; ++ni)
            #pragma unroll
            for (int r = 0; r < 4; ++r)
                xz[(size_t)(p0 + mi * 16 + lg * 4 + r) * 1024 + nbase + ni * 16 + l15] =
                    acc[mi][ni][r];
}

// ---------------- K2: causal depthwise conv(4) + SiLU (scan-order output) ----------------
__global__ __launch_bounds__(512) void k_conv(
    const float* __restrict__ xz, const float* __restrict__ cw,
    const float* __restrict__ cb, float* __restrict__ xc, int rev)
{
    const int bp = blockIdx.x;
    const int d  = threadIdx.x;
    const float w0 = cw[d * 4 + 0], w1 = cw[d * 4 + 1], w2 = cw[d * 4 + 2], w3 = cw[d * 4 + 3];
    const float bb = cb[d];
    float p1 = 0.f, p2 = 0.f, p3 = 0.f;
    for (int i = 0; i < 64; ++i) {
        int l = rev ? 63 - i : i;
        float cur = xz[((size_t)bp * 64 + l) * 1024 + d];
        float y = w3 * cur + w2 * p1 + w1 * p2 + w0 * p3 + bb;
        xc[((size_t)bp * 64 + i) * 512 + d] = siluf(y);
        p3 = p2; p2 = p1; p1 = cur;
    }
}

// ---------------- K3: x_proj (512 -> 48) + dt_proj (16 -> 512) + softplus ----------------
__global__ __launch_bounds__(256) void k_xdt(
    const float* __restrict__ xc, const float* __restrict__ W6,
    const float* __restrict__ dtw, const float* __restrict__ dtb,
    float* __restrict__ delta, float* __restrict__ bcb)
{
    __shared__ float sx2[16][512];
    __shared__ float sdbl[16][48];
    const int p0  = blockIdx.x * 16;
    const int tid = threadIdx.x;

    // load 16x512 contiguous tile
    {
        const float4* src = (const float4*)(xc + (size_t)p0 * 512);
        float4* dst = (float4*)&sx2[0][0];
        #pragma unroll
        for (int q = 0; q < 8; ++q) dst[q * 256 + tid] = src[q * 256 + tid];
    }
    __syncthreads();

    // x_proj: 16 pos x 48 outputs = 768 = 3*256
    #pragma unroll
    for (int k = 0; k < 3; ++k) {
        int o = k * 256 + tid;
        int p = o / 48, e = o - p * 48;
        const float4* wr = (const float4*)(W6 + (size_t)e * 512);
        float a = 0.f;
        for (int c4 = 0; c4 < 128; ++c4) {
            float4 w = wr[c4];
            float4 xv = *(const float4*)&sx2[p][c4 * 4];
            a = fmaf(w.x, xv.x, a); a = fmaf(w.y, xv.y, a);
            a = fmaf(w.z, xv.z, a); a = fmaf(w.w, xv.w, a);
        }
        sdbl[p][e] = a;
    }
    __syncthreads();

    // dt_proj + softplus: 16 pos x 512 d = 8192 = 32*256
    #pragma unroll
    for (int k = 0; k < 32; ++k) {
        int o = k * 256 + tid;
        int p = o >> 9, d = o & 511;
        const float4* wr = (const float4*)(dtw + (size_t)d * 16);
        float a = dtb[d];
        #pragma unroll
        for (int r4 = 0; r4 < 4; ++r4) {
            float4 w = wr[r4];
            float4 xv = *(const float4*)&sdbl[p][r4 * 4];
            a = fmaf(w.x, xv.x, a); a = fmaf(w.y, xv.y, a);
            a = fmaf(w.z, xv.z, a); a = fmaf(w.w, xv.w, a);
        }
        delta[(size_t)(p0 + p) * 512 + d] = softplusf(a);
    }
    // B and C: 16 pos x 32 = 512 = 2*256
    #pragma unroll
    for (int k = 0; k < 2; ++k) {
        int o = k * 256 + tid;
        int p = o >> 5, n = o & 31;
        bcb[(size_t)(p0 + p) * 32 + n] = sdbl[p][16 + n];
    }
}

// ---------------- K4: selective scan + D*u + SiLU(z) gate ----------------
__global__ __launch_bounds__(256) void k_scan(
    const float* __restrict__ delta, const float* __restrict__ u_,
    const float* __restrict__ bc_, const float* __restrict__ xz,
    const float* __restrict__ A_log, const float* __restrict__ Dp,
    float* __restrict__ yacc, int rev)
{
    const int bid = blockIdx.x;
    const int bp  = bid >> 1;
    const int d   = ((bid & 1) << 8) + threadIdx.x;

    float a[16];
    #pragma unroll
    for (int n = 0; n < 16; ++n) a[n] = -__expf(A_log[(size_t)d * 16 + n]);
    const float Dd = Dp[d];

    float h[16];
    #pragma unroll
    for (int n = 0; n < 16; ++n) h[n] = 0.f;

    for (int l = 0; l < 64; ++l) {
        size_t base = (size_t)bp * 64 + l;
        float dl = delta[base * 512 + d];
        float uu = u_[base * 512 + d];
        float du = dl * uu;
        const float4* bc = (const float4*)(bc_ + base * 32);
        float y = 0.f;
        #pragma unroll
        for (int n4 = 0; n4 < 4; ++n4) {
            float4 Bv = bc[n4];
            float4 Cv = bc[4 + n4];
            int n = n4 * 4;
            h[n + 0] = fmaf(__expf(dl * a[n + 0]), h[n + 0], du * Bv.x); y = fmaf(h[n + 0], Cv.x, y);
            h[n + 1] = fmaf(__expf(dl * a[n + 1]), h[n + 1], du * Bv.y); y = fmaf(h[n + 1], Cv.y, y);
            h[n + 2] = fmaf(__expf(dl * a[n + 2]), h[n + 2], du * Bv.z); y = fmaf(h[n + 2], Cv.z, y);
            h[n + 3] = fmaf(__expf(dl * a[n + 3]), h[n + 3], du * Bv.w); y = fmaf(h[n + 3], Cv.w, y);
        }
        y = fmaf(Dd, uu, y);
        int lo = rev ? 63 - l : l;
        float zv = xz[((size_t)bp * 64 + lo) * 1024 + 512 + d];
        float out = y * siluf(zv);
        float* dst = yacc + ((size_t)bp * 64 + lo) * 512 + d;
        if (rev) *dst += out;
        else     *dst  = out;
    }
}

// ---------------- K5: out_proj (512 -> 256) + un-shuffle + residual ----------------
// Block handles 16 positions strided by 64: {(bp0+i)*64 + l}, so output writes are float4.
__global__ __launch_bounds__(256) void k_outproj(
    const float* __restrict__ yacc, const float* __restrict__ Wout,
    const float* __restrict__ x, float* __restrict__ out)
{
    __shared__ float sy[16][512];
    const int blk = blockIdx.x;           // g*64 + l
    const int g = blk >> 6, l = blk & 63;
    const int bp0 = g * 16;
    const int b = bp0 >> 6, pp0 = bp0 & 63;
    const int tid = threadIdx.x;

    #pragma unroll
    for (int q = 0; q < 8; ++q) {
        int fq = q * 256 + tid;           // float4 index over 16x512 tile
        int i = fq >> 7, d4 = fq & 127;
        ((float4*)&sy[i][0])[d4] =
            *(const float4*)(yacc + ((size_t)(bp0 + i) * 64 + l) * 512 + d4 * 4);
    }
    __syncthreads();

    const int c = tid;
    float acc[16];
    #pragma unroll
    for (int i = 0; i < 16; ++i) acc[i] = 0.f;
    const float4* wr = (const float4*)(Wout + (size_t)c * 512);
    for (int d4 = 0; d4 < 128; ++d4) {
        float4 w = wr[d4];
        #pragma unroll
        for (int i = 0; i < 16; ++i) {
            float4 xv = *(const float4*)&sy[i][d4 * 4];
            acc[i] = fmaf(w.x, xv.x, acc[i]);
            acc[i] = fmaf(w.y, xv.y, acc[i]);
            acc[i] = fmaf(w.z, xv.z, acc[i]);
            acc[i] = fmaf(w.w, xv.w, acc[i]);
        }
    }
    #pragma unroll
    for (int i4 = 0; i4 < 4; ++i4) {
        size_t idx = ((size_t)(b * 256 + c)) * 4096 + (size_t)l * 64 + pp0 + i4 * 4;
        float4 xr = *(const float4*)(x + idx);
        float4 v;
        v.x = acc[i4 * 4 + 0] + xr.x;
        v.y = acc[i4 * 4 + 1] + xr.y;
        v.z = acc[i4 * 4 + 2] + xr.z;
        v.w = acc[i4 * 4 + 3] + xr.w;
        *(float4*)(out + idx) = v;
    }
}

extern "C" void kernel_launch(void* const* d_in, const int* in_sizes, int n_in,
                              void* d_out, int out_size, void* d_ws, size_t ws_size,
                              hipStream_t stream) {
    const float* x        = (const float*)d_in[0];
    const float* ln_g     = (const float*)d_in[1];
    const float* ln_b     = (const float*)d_in[2];
    const float* in_w     = (const float*)d_in[3];
    const float* conv_w   = (const float*)d_in[4];
    const float* conv_b   = (const float*)d_in[5];
    const float* xproj_w  = (const float*)d_in[6];
    const float* dtp_w    = (const float*)d_in[7];
    const float* dtp_b    = (const float*)d_in[8];
    const float* A_log    = (const float*)d_in[9];
    const float* D_f      = (const float*)d_in[10];
    const float* conv_w_b = (const float*)d_in[11];
    const float* conv_b_b = (const float*)d_in[12];
    const float* xproj_wb = (const float*)d_in[13];
    const float* dtp_w_b  = (const float*)d_in[14];
    const float* dtp_b_b  = (const float*)d_in[15];
    const float* A_b_log  = (const float*)d_in[16];
    const float* D_b      = (const float*)d_in[17];
    const float* out_w    = (const float*)d_in[18];
    float* out = (float*)d_out;

    float* ws  = (float*)d_ws;
    float* xz  = ws + OFF_XZ;
    float* xc  = ws + OFF_XC;
    float* dl  = ws + OFF_DL;
    float* bc  = ws + OFF_BC;
    float* ya  = ws + OFF_YA;
    unsigned short* w_bf = (unsigned short*)(ws + OFF_BC);  // BC region free until k_xdt

    // 0. convert in_proj weight to bf16 (re-done every launch; ws is re-poisoned)
    k_cvt_w<<<256, 256, 0, stream>>>(in_w, w_bf);
    // 1. LN + in_proj (bf16 MFMA)
    k_ln_inproj_mfma<<<512, 256, 0, stream>>>(x, ln_g, ln_b, w_bf, xz);
    // forward branch
    k_conv<<<128, 512, 0, stream>>>(xz, conv_w, conv_b, xc, 0);
    k_xdt<<<512, 256, 0, stream>>>(xc, xproj_w, dtp_w, dtp_b, dl, bc);
    k_scan<<<256, 256, 0, stream>>>(dl, xc, bc, xz, A_log, D_f, ya, 0);
    // backward branch (reversed scan order, buffers reused)
    k_conv<<<128, 512, 0, stream>>>(xz, conv_w_b, conv_b_b, xc, 1);
    k_xdt<<<512, 256, 0, stream>>>(xc, xproj_wb, dtp_w_b, dtp_b_b, dl, bc);
    k_scan<<<256, 256, 0, stream>>>(dl, xc, bc, xz, A_b_log, D_b, ya, 1);
    // out_proj + scatter + residual
    k_outproj<<<512, 256, 0, stream>>>(ya, out_w, x, out);
}

// Round 7
// 400.196 us; speedup vs baseline: 1.5665x; 1.3661x over previous
//
#include <hip/hip_runtime.h>

// BiPixelMambaLayer: D_MODEL=256, D_INNER=512, D_STATE=16, D_CONV=4, DT_RANK=16, PATCH=64
// x: (2, 256, 4096) fp32.  Mamba batch B'=128 (= 2*64), seq NPT=64, channels along patch axis.
// xd[b*64+p, c, n] = x[b, c, n*64+p]
//
// Workspace layout (floats), total ~85 MB:
//   XZ  [128][64][1024]  = 8388608   (xz, position-major: [b'][l][e])
//   XC  [128][64][512]   = 4194304   (conv+silu output, scan-order per branch; reused fwd/bwd)
//   DL  [128][64][512]   = 4194304   (delta, softplus'd; reused)
//   BCB [128][64][32]    = 262144    (B then C per position; reused)  -- also holds W_bf16 during K1
//   YA  [128][64][512]   = 4194304   (gated y accumulator: fwd '=' then bwd '+=')

#define OFF_XZ 0
#define OFF_XC 8388608
#define OFF_DL 12582912
#define OFF_BC 16777216
#define OFF_YA 17039360

typedef __attribute__((ext_vector_type(8))) short short8;
typedef __attribute__((ext_vector_type(4))) float f32x4;

__device__ __forceinline__ float siluf(float v) {
    return v / (1.f + __expf(-v));
}
__device__ __forceinline__ float softplusf(float v) {
    return (v > 20.f) ? v : log1pf(__expf(v));
}
__device__ __forceinline__ unsigned short f2bf(float f) {
    union { float f; unsigned int u; } v; v.f = f;
    unsigned int u = v.u;
    return (unsigned short)((u + 0x7FFFu + ((u >> 16) & 1u)) >> 16);
}

// ---------------- K0: convert in_proj W (1024x256 fp32) to bf16 ----------------
__global__ __launch_bounds__(256) void k_cvt_w(
    const float* __restrict__ W, unsigned short* __restrict__ Wb)
{
    int i = (blockIdx.x * 256 + threadIdx.x) * 4;   // 262144 elems / 4
    float4 v = *(const float4*)(W + i);
    ushort4 o;
    o.x = f2bf(v.x); o.y = f2bf(v.y); o.z = f2bf(v.z); o.w = f2bf(v.w);
    *(ushort4*)(Wb + i) = o;
}

// ---------------- K1: LayerNorm + in_proj (256 -> 1024) via bf16 MFMA ----------------
// Grid: 512 = 128 pos-groups (64 pos each, == one bp row, l=0..63) x 4 out-groups (256 cols).
// Block: 256 thr = 4 waves. Wave computes 64 pos x 64 cols as 4x4 tiles of 16x16, K-loop 8x32.
__global__ __launch_bounds__(256) void k_ln_inproj_mfma(
    const float* __restrict__ x, const float* __restrict__ g,
    const float* __restrict__ bt, const unsigned short* __restrict__ Wb,
    float* __restrict__ xz)
{
    __shared__ unsigned short sxb[64 * 256];   // 32 KB, bf16, XOR-swizzled rows of 512B
    const int bid = blockIdx.x;
    const int pg = bid >> 2, og = bid & 3;
    const int p0 = pg * 64;                    // pos-group base; bp = pg, l = row m
    const int tid = threadIdx.x;
    const int wave = tid >> 6, lane = tid & 63;
    const int b = pg >> 6, pp = pg & 63;
    const float* xb = x + ((size_t)b * 256) * 4096 + pp;

    // ---- Phase 1: LN for 64 positions (wave w: rows w*16..w*16+15; lane: 4 channels) ----
    const int c = lane * 4;
    const float g0 = g[c + 0], g1 = g[c + 1], g2 = g[c + 2], g3 = g[c + 3];
    const float b0 = bt[c + 0], b1 = bt[c + 1], b2 = bt[c + 2], b3 = bt[c + 3];
    for (int i = 0; i < 16; ++i) {
        int m = wave * 16 + i;                 // row in tile == l
        const float* xr = xb + m * 64;
        float v0 = xr[(size_t)(c + 0) * 4096];
        float v1 = xr[(size_t)(c + 1) * 4096];
        float v2 = xr[(size_t)(c + 2) * 4096];
        float v3 = xr[(size_t)(c + 3) * 4096];
        float s = v0 + v1 + v2 + v3;
        #pragma unroll
        for (int o = 32; o; o >>= 1) s += __shfl_xor(s, o);
        float mu = s * (1.f / 256.f);
        float q0 = v0 - mu, q1 = v1 - mu, q2 = v2 - mu, q3 = v3 - mu;
        float q = q0 * q0 + q1 * q1 + q2 * q2 + q3 * q3;
        #pragma unroll
        for (int o = 32; o; o >>= 1) q += __shfl_xor(q, o);
        float rs = rsqrtf(q * (1.f / 256.f) + 1e-5f);
        ushort4 pk;
        pk.x = f2bf(q0 * rs * g0 + b0);
        pk.y = f2bf(q1 * rs * g1 + b1);
        pk.z = f2bf(q2 * rs * g2 + b2);
        pk.w = f2bf(q3 * rs * g3 + b3);
        int byte = m * 512 + lane * 8;
        byte ^= (m & 7) << 4;                  // T2 swizzle: spread 512B-stride rows over banks
        *(ushort4*)((char*)sxb + byte) = pk;
    }
    __syncthreads();

    // ---- Phase 2: MFMA GEMM. acc[mi][ni] over 4x4 tiles of 16x16, K = 256 in 8 steps ----
    const int nbase = og * 256 + wave * 64;    // wave's first output column
    const int l15 = lane & 15, lg = lane >> 4; // fragment row / k-group
    f32x4 acc[4][4];
    #pragma unroll
    for (int mi = 0; mi < 4; ++mi)
        #pragma unroll
        for (int ni = 0; ni < 4; ++ni) acc[mi][ni] = (f32x4){0.f, 0.f, 0.f, 0.f};

    // per-lane W row pointers (W stored [N][K] row-major = B^T input pattern)
    const unsigned short* wrow[4];
    #pragma unroll
    for (int ni = 0; ni < 4; ++ni)
        wrow[ni] = Wb + (size_t)(nbase + ni * 16 + l15) * 256 + lg * 8;

    #pragma unroll 2
    for (int k0 = 0; k0 < 256; k0 += 32) {
        short8 a[4], bfr[4];
        #pragma unroll
        for (int mi = 0; mi < 4; ++mi) {
            int row = mi * 16 + l15;
            int byte = row * 512 + k0 * 2 + lg * 16;
            byte ^= (row & 7) << 4;
            a[mi] = *(const short8*)((const char*)sxb + byte);
        }
        #pragma unroll
        for (int ni = 0; ni < 4; ++ni)
            bfr[ni] = *(const short8*)(wrow[ni] + k0);
        #pragma unroll
        for (int mi = 0; mi < 4; ++mi)
            #pragma unroll
            for (int ni = 0; ni < 4; ++ni)
                acc[mi][ni] = __builtin_amdgcn_mfma_f32_16x16x32_bf16(
                    a[mi], bfr[ni], acc[mi][ni], 0, 0, 0);
    }

    // ---- Epilogue: D[m][n], m = mi*16 + lg*4 + r, n = nbase + ni*16 + l15 ----
    #pragma unroll
    for (int mi = 0; mi < 4; ++mi)
        #pragma unroll
        for (int ni = 0; ni < 4; ++ni)
            #pragma unroll
            for (int r = 0; r < 4; ++r)
                xz[(size_t)(p0 + mi * 16 + lg * 4 + r) * 1024 + nbase + ni * 16 + l15] =
                    acc[mi][ni][r];
}

// ---------------- K2: fused causal dwconv(4)+SiLU + x_proj + dt_proj + softplus --------
// Block: 16 scan-order positions of one bp row (grid 512 = 128 bp x 4).
// LDS: sx2[16][516] (padded: 516%32==4 -> 2-way max), sdtw transposed, sdbl.
__global__ __launch_bounds__(256) void k_cxdt(
    const float* __restrict__ xz, const float* __restrict__ cw,
    const float* __restrict__ cb, const float* __restrict__ W6,
    const float* __restrict__ dtw, const float* __restrict__ dtb,
    float* __restrict__ xc, float* __restrict__ delta,
    float* __restrict__ bcb, int rev)
{
    __shared__ float sx2[16][516];
    __shared__ float sdtw[16][512];
    __shared__ float sdbl[16][48];
    const int blk = blockIdx.x;
    const int bp  = blk >> 2;
    const int i0  = (blk & 3) << 4;     // first scan-order position of this tile
    const int tid = threadIdx.x;

    // ---- stage dt_proj weight transposed: sdtw[r][d] = dtw[d][r] ----
    #pragma unroll
    for (int q = 0; q < 8; ++q) {
        int f4 = q * 256 + tid;          // float4 id over [512][16]
        int d = f4 >> 2, r0 = (f4 & 3) * 4;
        float4 w = *(const float4*)(dtw + d * 16 + r0);
        sdtw[r0 + 0][d] = w.x;
        sdtw[r0 + 1][d] = w.y;
        sdtw[r0 + 2][d] = w.z;
        sdtw[r0 + 3][d] = w.w;
    }

    // ---- conv + silu into sx2 (and xc for the scan's u) ----
    // thread handles 2 d-columns; 3-tap register history, seeded from xz.
    const size_t xzrow = (size_t)bp * 64;
    #pragma unroll
    for (int half = 0; half < 2; ++half) {
        int d = half * 256 + tid;
        float w0 = cw[d * 4 + 0], w1 = cw[d * 4 + 1], w2 = cw[d * 4 + 2], w3 = cw[d * 4 + 3];
        float bb = cb[d];
        float p1 = 0.f, p2 = 0.f, p3 = 0.f;
        if (i0 > 0) {
            p1 = xz[(xzrow + (rev ? 63 - (i0 - 1) : i0 - 1)) * 1024 + d];
            p2 = xz[(xzrow + (rev ? 63 - (i0 - 2) : i0 - 2)) * 1024 + d];
            p3 = xz[(xzrow + (rev ? 63 - (i0 - 3) : i0 - 3)) * 1024 + d];
        }
        for (int p = 0; p < 16; ++p) {
            int i = i0 + p;
            int l = rev ? 63 - i : i;
            float cur = xz[(xzrow + l) * 1024 + d];
            float y = w3 * cur + w2 * p1 + w1 * p2 + w0 * p3 + bb;
            float s = siluf(y);
            sx2[p][d] = s;
            xc[(xzrow + i) * 512 + d] = s;
            p3 = p2; p2 = p1; p1 = cur;
        }
    }
    __syncthreads();

    // ---- x_proj: 768 outputs, e-major (16-lane weight broadcast) ----
    #pragma unroll
    for (int k = 0; k < 3; ++k) {
        int o = k * 256 + tid;
        int e = o >> 4, p = o & 15;
        const float4* wr = (const float4*)(W6 + (size_t)e * 512);
        float a = 0.f;
        for (int c4 = 0; c4 < 128; ++c4) {
            float4 w = wr[c4];
            float4 xv = *(const float4*)&sx2[p][c4 * 4];
            a = fmaf(w.x, xv.x, a); a = fmaf(w.y, xv.y, a);
            a = fmaf(w.z, xv.z, a); a = fmaf(w.w, xv.w, a);
        }
        sdbl[p][e] = a;
    }
    __syncthreads();

    // ---- dt_proj + softplus: 16 pos x 512 d; sdtw scalar reads are conflict-free ----
    #pragma unroll
    for (int k = 0; k < 32; ++k) {
        int o = k * 256 + tid;
        int p = o >> 9, d = o & 511;
        float a = dtb[d];
        #pragma unroll
        for (int r = 0; r < 16; ++r)
            a = fmaf(sdtw[r][d], sdbl[p][r], a);
        delta[(xzrow + i0 + p) * 512 + d] = softplusf(a);
    }
    // ---- B and C passthrough ----
    #pragma unroll
    for (int k = 0; k < 2; ++k) {
        int o = k * 256 + tid;
        int p = o >> 5, n = o & 31;
        bcb[(xzrow + i0 + p) * 32 + n] = sdbl[p][16 + n];
    }
}

// ---------------- K4: selective scan + D*u + SiLU(z) gate ----------------
__global__ __launch_bounds__(256) void k_scan(
    const float* __restrict__ delta, const float* __restrict__ u_,
    const float* __restrict__ bc_, const float* __restrict__ xz,
    const float* __restrict__ A_log, const float* __restrict__ Dp,
    float* __restrict__ yacc, int rev)
{
    const int bid = blockIdx.x;
    const int bp  = bid >> 1;
    const int d   = ((bid & 1) << 8) + threadIdx.x;

    float a[16];
    #pragma unroll
    for (int n = 0; n < 16; ++n) a[n] = -__expf(A_log[(size_t)d * 16 + n]);
    const float Dd = Dp[d];

    float h[16];
    #pragma unroll
    for (int n = 0; n < 16; ++n) h[n] = 0.f;

    for (int l = 0; l < 64; ++l) {
        size_t base = (size_t)bp * 64 + l;
        float dl = delta[base * 512 + d];
        float uu = u_[base * 512 + d];
        float du = dl * uu;
        const float4* bc = (const float4*)(bc_ + base * 32);
        float y = 0.f;
        #pragma unroll
        for (int n4 = 0; n4 < 4; ++n4) {
            float4 Bv = bc[n4];
            float4 Cv = bc[4 + n4];
            int n = n4 * 4;
            h[n + 0] = fmaf(__expf(dl * a[n + 0]), h[n + 0], du * Bv.x); y = fmaf(h[n + 0], Cv.x, y);
            h[n + 1] = fmaf(__expf(dl * a[n + 1]), h[n + 1], du * Bv.y); y = fmaf(h[n + 1], Cv.y, y);
            h[n + 2] = fmaf(__expf(dl * a[n + 2]), h[n + 2], du * Bv.z); y = fmaf(h[n + 2], Cv.z, y);
            h[n + 3] = fmaf(__expf(dl * a[n + 3]), h[n + 3], du * Bv.w); y = fmaf(h[n + 3], Cv.w, y);
        }
        y = fmaf(Dd, uu, y);
        int lo = rev ? 63 - l : l;
        float zv = xz[((size_t)bp * 64 + lo) * 1024 + 512 + d];
        float out = y * siluf(zv);
        float* dst = yacc + ((size_t)bp * 64 + lo) * 512 + d;
        if (rev) *dst += out;
        else     *dst  = out;
    }
}

// ---------------- K5: out_proj (512 -> 256) + un-shuffle + residual ----------------
// Block handles 16 positions strided by 64: {(bp0+i)*64 + l}, so output writes are float4.
__global__ __launch_bounds__(256) void k_outproj(
    const float* __restrict__ yacc, const float* __restrict__ Wout,
    const float* __restrict__ x, float* __restrict__ out)
{
    __shared__ float sy[16][512];
    const int blk = blockIdx.x;           // g*64 + l
    const int g = blk >> 6, l = blk & 63;
    const int bp0 = g * 16;
    const int b = bp0 >> 6, pp0 = bp0 & 63;
    const int tid = threadIdx.x;

    #pragma unroll
    for (int q = 0; q < 8; ++q) {
        int fq = q * 256 + tid;           // float4 index over 16x512 tile
        int i = fq >> 7, d4 = fq & 127;
        ((float4*)&sy[i][0])[d4] =
            *(const float4*)(yacc + ((size_t)(bp0 + i) * 64 + l) * 512 + d4 * 4);
    }
    __syncthreads();

    const int c = tid;
    float acc[16];
    #pragma unroll
    for (int i = 0; i < 16; ++i) acc[i] = 0.f;
    const float4* wr = (const float4*)(Wout + (size_t)c * 512);
    for (int d4 = 0; d4 < 128; ++d4) {
        float4 w = wr[d4];
        #pragma unroll
        for (int i = 0; i < 16; ++i) {
            float4 xv = *(const float4*)&sy[i][d4 * 4];
            acc[i] = fmaf(w.x, xv.x, acc[i]);
            acc[i] = fmaf(w.y, xv.y, acc[i]);
            acc[i] = fmaf(w.z, xv.z, acc[i]);
            acc[i] = fmaf(w.w, xv.w, acc[i]);
        }
    }
    #pragma unroll
    for (int i4 = 0; i4 < 4; ++i4) {
        size_t idx = ((size_t)(b * 256 + c)) * 4096 + (size_t)l * 64 + pp0 + i4 * 4;
        float4 xr = *(const float4*)(x + idx);
        float4 v;
        v.x = acc[i4 * 4 + 0] + xr.x;
        v.y = acc[i4 * 4 + 1] + xr.y;
        v.z = acc[i4 * 4 + 2] + xr.z;
        v.w = acc[i4 * 4 + 3] + xr.w;
        *(float4*)(out + idx) = v;
    }
}

extern "C" void kernel_launch(void* const* d_in, const int* in_sizes, int n_in,
                              void* d_out, int out_size, void* d_ws, size_t ws_size,
                              hipStream_t stream) {
    const float* x        = (const float*)d_in[0];
    const float* ln_g     = (const float*)d_in[1];
    const float* ln_b     = (const float*)d_in[2];
    const float* in_w     = (const float*)d_in[3];
    const float* conv_w   = (const float*)d_in[4];
    const float* conv_b   = (const float*)d_in[5];
    const float* xproj_w  = (const float*)d_in[6];
    const float* dtp_w    = (const float*)d_in[7];
    const float* dtp_b    = (const float*)d_in[8];
    const float* A_log    = (const float*)d_in[9];
    const float* D_f      = (const float*)d_in[10];
    const float* conv_w_b = (const float*)d_in[11];
    const float* conv_b_b = (const float*)d_in[12];
    const float* xproj_wb = (const float*)d_in[13];
    const float* dtp_w_b  = (const float*)d_in[14];
    const float* dtp_b_b  = (const float*)d_in[15];
    const float* A_b_log  = (const float*)d_in[16];
    const float* D_b      = (const float*)d_in[17];
    const float* out_w    = (const float*)d_in[18];
    float* out = (float*)d_out;

    float* ws  = (float*)d_ws;
    float* xz  = ws + OFF_XZ;
    float* xc  = ws + OFF_XC;
    float* dl  = ws + OFF_DL;
    float* bc  = ws + OFF_BC;
    float* ya  = ws + OFF_YA;
    unsigned short* w_bf = (unsigned short*)(ws + OFF_BC);  // BC region free until k_cxdt

    // 0. convert in_proj weight to bf16 (re-done every launch; ws is re-poisoned)
    k_cvt_w<<<256, 256, 0, stream>>>(in_w, w_bf);
    // 1. LN + in_proj (bf16 MFMA)
    k_ln_inproj_mfma<<<512, 256, 0, stream>>>(x, ln_g, ln_b, w_bf, xz);
    // forward branch: fused conv+xproj+dtproj, then scan
    k_cxdt<<<512, 256, 0, stream>>>(xz, conv_w, conv_b, xproj_w, dtp_w, dtp_b,
                                    xc, dl, bc, 0);
    k_scan<<<256, 256, 0, stream>>>(dl, xc, bc, xz, A_log, D_f, ya, 0);
    // backward branch (reversed scan order, buffers reused)
    k_cxdt<<<512, 256, 0, stream>>>(xz, conv_w_b, conv_b_b, xproj_wb, dtp_w_b, dtp_b_b,
                                    xc, dl, bc, 1);
    k_scan<<<256, 256, 0, stream>>>(dl, xc, bc, xz, A_b_log, D_b, ya, 1);
    // out_proj + scatter + residual
    k_outproj<<<512, 256, 0, stream>>>(ya, out_w, x, out);
}

// Round 9
// 351.484 us; speedup vs baseline: 1.7836x; 1.1386x over previous
//
#include <hip/hip_runtime.h>

// BiPixelMambaLayer: D_MODEL=256, D_INNER=512, D_STATE=16, D_CONV=4, DT_RANK=16, PATCH=64
// x: (2, 256, 4096) fp32.  Mamba batch B'=128 (= 2*64), seq NPT=64, channels along patch axis.
// xd[b*64+p, c, n] = x[b, c, n*64+p]
//
// Workspace layout (float slots), total ~85.2 MB:
//   XZ  [128][64][1024]       = 8388608
//   XC  [128][64][512]        = 4194304
//   DL  [128][64][512]        = 4194304
//   BCB [128][64][32]         = 262144   (first half doubles as in_proj W bf16 during K1)
//   YF  bf16 [128][64][512]   = 2097152 float-slots
//   YB  bf16 [128][64][512]   = 2097152 float-slots
//   WOB bf16 [256][512]       = 65536 float-slots

#define OFF_XZ 0
#define OFF_XC 8388608
#define OFF_DL 12582912
#define OFF_BC 16777216
#define OFF_YF 17039360
#define OFF_YB 19136512
#define OFF_WOB 21233664

typedef __attribute__((ext_vector_type(8))) short short8;
typedef __attribute__((ext_vector_type(4))) float f32x4;

__device__ __forceinline__ float siluf(float v) {
    return v / (1.f + __expf(-v));
}
__device__ __forceinline__ float softplusf(float v) {
    return (v > 20.f) ? v : log1pf(__expf(v));
}
__device__ __forceinline__ unsigned short f2bf(float f) {
    union { float f; unsigned int u; } v; v.f = f;
    unsigned int u = v.u;
    return (unsigned short)((u + 0x7FFFu + ((u >> 16) & 1u)) >> 16);
}

// ---------------- K0: fp32 -> bf16 weight convert (generic) ----------------
__global__ __launch_bounds__(256) void k_cvt_w(
    const float* __restrict__ W, unsigned short* __restrict__ Wb, int n4)
{
    int i = blockIdx.x * 256 + threadIdx.x;
    if (i >= n4) return;
    float4 v = *(const float4*)(W + i * 4);
    ushort4 o;
    o.x = f2bf(v.x); o.y = f2bf(v.y); o.z = f2bf(v.z); o.w = f2bf(v.w);
    *(ushort4*)(Wb + i * 4) = o;
}

// ---------------- K1: LayerNorm + in_proj (256 -> 1024) via bf16 MFMA ----------------
__global__ __launch_bounds__(256) void k_ln_inproj_mfma(
    const float* __restrict__ x, const float* __restrict__ g,
    const float* __restrict__ bt, const unsigned short* __restrict__ Wb,
    float* __restrict__ xz)
{
    __shared__ unsigned short sxb[64 * 256];   // 32 KB, bf16, XOR-swizzled rows of 512B
    const int bid = blockIdx.x;
    const int pg = bid >> 2, og = bid & 3;
    const int p0 = pg * 64;
    const int tid = threadIdx.x;
    const int wave = tid >> 6, lane = tid & 63;
    const int b = pg >> 6, pp = pg & 63;
    const float* xb = x + ((size_t)b * 256) * 4096 + pp;

    const int c = lane * 4;
    const float g0 = g[c + 0], g1 = g[c + 1], g2 = g[c + 2], g3 = g[c + 3];
    const float b0 = bt[c + 0], b1 = bt[c + 1], b2 = bt[c + 2], b3 = bt[c + 3];
    for (int i = 0; i < 16; ++i) {
        int m = wave * 16 + i;
        const float* xr = xb + m * 64;
        float v0 = xr[(size_t)(c + 0) * 4096];
        float v1 = xr[(size_t)(c + 1) * 4096];
        float v2 = xr[(size_t)(c + 2) * 4096];
        float v3 = xr[(size_t)(c + 3) * 4096];
        float s = v0 + v1 + v2 + v3;
        #pragma unroll
        for (int o = 32; o; o >>= 1) s += __shfl_xor(s, o);
        float mu = s * (1.f / 256.f);
        float q0 = v0 - mu, q1 = v1 - mu, q2 = v2 - mu, q3 = v3 - mu;
        float q = q0 * q0 + q1 * q1 + q2 * q2 + q3 * q3;
        #pragma unroll
        for (int o = 32; o; o >>= 1) q += __shfl_xor(q, o);
        float rs = rsqrtf(q * (1.f / 256.f) + 1e-5f);
        ushort4 pk;
        pk.x = f2bf(q0 * rs * g0 + b0);
        pk.y = f2bf(q1 * rs * g1 + b1);
        pk.z = f2bf(q2 * rs * g2 + b2);
        pk.w = f2bf(q3 * rs * g3 + b3);
        int byte = m * 512 + lane * 8;
        byte ^= (m & 7) << 4;
        *(ushort4*)((char*)sxb + byte) = pk;
    }
    __syncthreads();

    const int nbase = og * 256 + wave * 64;
    const int l15 = lane & 15, lg = lane >> 4;
    f32x4 acc[4][4];
    #pragma unroll
    for (int mi = 0; mi < 4; ++mi)
        #pragma unroll
        for (int ni = 0; ni < 4; ++ni) acc[mi][ni] = (f32x4){0.f, 0.f, 0.f, 0.f};

    const unsigned short* wrow[4];
    #pragma unroll
    for (int ni = 0; ni < 4; ++ni)
        wrow[ni] = Wb + (size_t)(nbase + ni * 16 + l15) * 256 + lg * 8;

    #pragma unroll 2
    for (int k0 = 0; k0 < 256; k0 += 32) {
        short8 a[4], bfr[4];
        #pragma unroll
        for (int mi = 0; mi < 4; ++mi) {
            int row = mi * 16 + l15;
            int byte = row * 512 + k0 * 2 + lg * 16;
            byte ^= (row & 7) << 4;
            a[mi] = *(const short8*)((const char*)sxb + byte);
        }
        #pragma unroll
        for (int ni = 0; ni < 4; ++ni)
            bfr[ni] = *(const short8*)(wrow[ni] + k0);
        #pragma unroll
        for (int mi = 0; mi < 4; ++mi)
            #pragma unroll
            for (int ni = 0; ni < 4; ++ni)
                acc[mi][ni] = __builtin_amdgcn_mfma_f32_16x16x32_bf16(
                    a[mi], bfr[ni], acc[mi][ni], 0, 0, 0);
    }

    #pragma unroll
    for (int mi = 0; mi < 4; ++mi)
        #pragma unroll
        for (int ni = 0; ni < 4; ++ni)
            #pragma unroll
            for (int r = 0; r < 4; ++r)
                xz[(size_t)(p0 + mi * 16 + lg * 4 + r) * 1024 + nbase + ni * 16 + l15] =
                    acc[mi][ni][r];
}

// ---------------- K2: fused causal dwconv(4)+SiLU + x_proj + dt_proj + softplus --------
__global__ __launch_bounds__(256) void k_cxdt(
    const float* __restrict__ xz, const float* __restrict__ cw,
    const float* __restrict__ cb, const float* __restrict__ W6,
    const float* __restrict__ dtw, const float* __restrict__ dtb,
    float* __restrict__ xc, float* __restrict__ delta,
    float* __restrict__ bcb, int rev)
{
    __shared__ float sx2[16][516];
    __shared__ float sdtw[16][512];
    __shared__ float sdbl[16][48];
    const int blk = blockIdx.x;
    const int bp  = blk >> 2;
    const int i0  = (blk & 3) << 4;
    const int tid = threadIdx.x;

    #pragma unroll
    for (int q = 0; q < 8; ++q) {
        int f4 = q * 256 + tid;
        int d = f4 >> 2, r0 = (f4 & 3) * 4;
        float4 w = *(const float4*)(dtw + d * 16 + r0);
        sdtw[r0 + 0][d] = w.x;
        sdtw[r0 + 1][d] = w.y;
        sdtw[r0 + 2][d] = w.z;
        sdtw[r0 + 3][d] = w.w;
    }

    const size_t xzrow = (size_t)bp * 64;
    #pragma unroll
    for (int half = 0; half < 2; ++half) {
        int d = half * 256 + tid;
        float w0 = cw[d * 4 + 0], w1 = cw[d * 4 + 1], w2 = cw[d * 4 + 2], w3 = cw[d * 4 + 3];
        float bb = cb[d];
        float p1 = 0.f, p2 = 0.f, p3 = 0.f;
        if (i0 > 0) {
            p1 = xz[(xzrow + (rev ? 63 - (i0 - 1) : i0 - 1)) * 1024 + d];
            p2 = xz[(xzrow + (rev ? 63 - (i0 - 2) : i0 - 2)) * 1024 + d];
            p3 = xz[(xzrow + (rev ? 63 - (i0 - 3) : i0 - 3)) * 1024 + d];
        }
        for (int p = 0; p < 16; ++p) {
            int i = i0 + p;
            int l = rev ? 63 - i : i;
            float cur = xz[(xzrow + l) * 1024 + d];
            float y = w3 * cur + w2 * p1 + w1 * p2 + w0 * p3 + bb;
            float s = siluf(y);
            sx2[p][d] = s;
            xc[(xzrow + i) * 512 + d] = s;
            p3 = p2; p2 = p1; p1 = cur;
        }
    }
    __syncthreads();

    #pragma unroll
    for (int k = 0; k < 3; ++k) {
        int o = k * 256 + tid;
        int e = o >> 4, p = o & 15;
        const float4* wr = (const float4*)(W6 + (size_t)e * 512);
        float a = 0.f;
        for (int c4 = 0; c4 < 128; ++c4) {
            float4 w = wr[c4];
            float4 xv = *(const float4*)&sx2[p][c4 * 4];
            a = fmaf(w.x, xv.x, a); a = fmaf(w.y, xv.y, a);
            a = fmaf(w.z, xv.z, a); a = fmaf(w.w, xv.w, a);
        }
        sdbl[p][e] = a;
    }
    __syncthreads();

    #pragma unroll
    for (int k = 0; k < 32; ++k) {
        int o = k * 256 + tid;
        int p = o >> 9, d = o & 511;
        float a = dtb[d];
        #pragma unroll
        for (int r = 0; r < 16; ++r)
            a = fmaf(sdtw[r][d], sdbl[p][r], a);
        delta[(xzrow + i0 + p) * 512 + d] = softplusf(a);
    }
    #pragma unroll
    for (int k = 0; k < 2; ++k) {
        int o = k * 256 + tid;
        int p = o >> 5, n = o & 31;
        bcb[(xzrow + i0 + p) * 32 + n] = sdbl[p][16 + n];
    }
}

// ---------------- K4: selective scan + D*u + SiLU(z) gate -> bf16 ----------------
__global__ __launch_bounds__(256) void k_scan(
    const float* __restrict__ delta, const float* __restrict__ u_,
    const float* __restrict__ bc_, const float* __restrict__ xz,
    const float* __restrict__ A_log, const float* __restrict__ Dp,
    unsigned short* __restrict__ yout, int rev)
{
    const int bid = blockIdx.x;
    const int bp  = bid >> 1;
    const int d   = ((bid & 1) << 8) + threadIdx.x;

    float a[16];
    #pragma unroll
    for (int n = 0; n < 16; ++n) a[n] = -__expf(A_log[(size_t)d * 16 + n]);
    const float Dd = Dp[d];

    float h[16];
    #pragma unroll
    for (int n = 0; n < 16; ++n) h[n] = 0.f;

    for (int l = 0; l < 64; ++l) {
        size_t base = (size_t)bp * 64 + l;
        float dl = delta[base * 512 + d];
        float uu = u_[base * 512 + d];
        float du = dl * uu;
        const float4* bc = (const float4*)(bc_ + base * 32);
        float y = 0.f;
        #pragma unroll
        for (int n4 = 0; n4 < 4; ++n4) {
            float4 Bv = bc[n4];
            float4 Cv = bc[4 + n4];
            int n = n4 * 4;
            h[n + 0] = fmaf(__expf(dl * a[n + 0]), h[n + 0], du * Bv.x); y = fmaf(h[n + 0], Cv.x, y);
            h[n + 1] = fmaf(__expf(dl * a[n + 1]), h[n + 1], du * Bv.y); y = fmaf(h[n + 1], Cv.y, y);
            h[n + 2] = fmaf(__expf(dl * a[n + 2]), h[n + 2], du * Bv.z); y = fmaf(h[n + 2], Cv.z, y);
            h[n + 3] = fmaf(__expf(dl * a[n + 3]), h[n + 3], du * Bv.w); y = fmaf(h[n + 3], Cv.w, y);
        }
        y = fmaf(Dd, uu, y);
        int lo = rev ? 63 - l : l;
        float zv = xz[((size_t)bp * 64 + lo) * 1024 + 512 + d];
        yout[((size_t)bp * 64 + lo) * 512 + d] = f2bf(y * siluf(zv));
    }
}

// ---------------- K5: out_proj (512 -> 256) via bf16 MFMA + un-shuffle + residual -----
// Grid 128 = g(2) x l(64). Block: 4 waves; wave owns 64 c. M = 64 bp (pp = m), K = 512
// over two A-streams (yf, yb) accumulated into one acc. Epilogue: LDS transpose ->
// coalesced float4 stores over pp with residual.
__global__ __launch_bounds__(256) void k_outproj_mfma(
    const unsigned short* __restrict__ yf, const unsigned short* __restrict__ yb,
    const unsigned short* __restrict__ wob, const float* __restrict__ x,
    float* __restrict__ out)
{
    __shared__ float sD[64][257];
    const int blk = blockIdx.x;
    const int g = blk >> 6, l = blk & 63;
    const int tid = threadIdx.x;
    const int wave = tid >> 6, lane = tid & 63;
    const int l15 = lane & 15, lg = lane >> 4;
    const int cbase = wave * 64;

    f32x4 acc[4][4];
    #pragma unroll
    for (int mi = 0; mi < 4; ++mi)
        #pragma unroll
        for (int ni = 0; ni < 4; ++ni) acc[mi][ni] = (f32x4){0.f, 0.f, 0.f, 0.f};

    const unsigned short* arf[4];
    const unsigned short* arb[4];
    #pragma unroll
    for (int mi = 0; mi < 4; ++mi) {
        size_t idx = (((size_t)(g * 64 + mi * 16 + l15)) * 64 + l) * 512 + lg * 8;
        arf[mi] = yf + idx;
        arb[mi] = yb + idx;
    }
    const unsigned short* brow[4];
    #pragma unroll
    for (int ni = 0; ni < 4; ++ni)
        brow[ni] = wob + (size_t)(cbase + ni * 16 + l15) * 512 + lg * 8;

    #pragma unroll 2
    for (int k0 = 0; k0 < 512; k0 += 32) {
        short8 bw[4], af[4], ab[4];
        #pragma unroll
        for (int ni = 0; ni < 4; ++ni) bw[ni] = *(const short8*)(brow[ni] + k0);
        #pragma unroll
        for (int mi = 0; mi < 4; ++mi) {
            af[mi] = *(const short8*)(arf[mi] + k0);
            ab[mi] = *(const short8*)(arb[mi] + k0);
        }
        #pragma unroll
        for (int mi = 0; mi < 4; ++mi)
            #pragma unroll
            for (int ni = 0; ni < 4; ++ni) {
                acc[mi][ni] = __builtin_amdgcn_mfma_f32_16x16x32_bf16(
                    af[mi], bw[ni], acc[mi][ni], 0, 0, 0);
                acc[mi][ni] = __builtin_amdgcn_mfma_f32_16x16x32_bf16(
                    ab[mi], bw[ni], acc[mi][ni], 0, 0, 0);
            }
    }

    // stage D[m=pp][c] into LDS (writes: same m, consecutive c -> conflict-free)
    #pragma unroll
    for (int mi = 0; mi < 4; ++mi)
        #pragma unroll
        for (int ni = 0; ni < 4; ++ni)
            #pragma unroll
            for (int r = 0; r < 4; ++r)
                sD[mi * 16 + lg * 4 + r][cbase + ni * 16 + l15] = acc[mi][ni][r];
    __syncthreads();

    // coalesced float4 stores over pp (+ residual)
    #pragma unroll
    for (int q = 0; q < 16; ++q) {
        int f4 = q * 256 + tid;          // [c:256][m4:16]
        int cc = f4 >> 4, m4 = f4 & 15;
        size_t idx = ((size_t)(g * 256 + cc)) * 4096 + (size_t)l * 64 + m4 * 4;
        float4 xr = *(const float4*)(x + idx);
        float4 v;
        v.x = sD[m4 * 4 + 0][cc] + xr.x;
        v.y = sD[m4 * 4 + 1][cc] + xr.y;
        v.z = sD[m4 * 4 + 2][cc] + xr.z;
        v.w = sD[m4 * 4 + 3][cc] + xr.w;
        *(float4*)(out + idx) = v;
    }
}

extern "C" void kernel_launch(void* const* d_in, const int* in_sizes, int n_in,
                              void* d_out, int out_size, void* d_ws, size_t ws_size,
                              hipStream_t stream) {
    const float* x        = (const float*)d_in[0];
    const float* ln_g     = (const float*)d_in[1];
    const float* ln_b     = (const float*)d_in[2];
    const float* in_w     = (const float*)d_in[3];
    const float* conv_w   = (const float*)d_in[4];
    const float* conv_b   = (const float*)d_in[5];
    const float* xproj_w  = (const float*)d_in[6];
    const float* dtp_w    = (const float*)d_in[7];
    const float* dtp_b    = (const float*)d_in[8];
    const float* A_log    = (const float*)d_in[9];
    const float* D_f      = (const float*)d_in[10];
    const float* conv_w_b = (const float*)d_in[11];
    const float* conv_b_b = (const float*)d_in[12];
    const float* xproj_wb = (const float*)d_in[13];
    const float* dtp_w_b  = (const float*)d_in[14];
    const float* dtp_b_b  = (const float*)d_in[15];
    const float* A_b_log  = (const float*)d_in[16];
    const float* D_b      = (const float*)d_in[17];
    const float* out_w    = (const float*)d_in[18];
    float* out = (float*)d_out;

    float* ws  = (float*)d_ws;
    float* xz  = ws + OFF_XZ;
    float* xc  = ws + OFF_XC;
    float* dl  = ws + OFF_DL;
    float* bc  = ws + OFF_BC;
    unsigned short* w_bf = (unsigned short*)(ws + OFF_BC);   // free until k_cxdt writes bcb
    unsigned short* yf   = (unsigned short*)(ws + OFF_YF);
    unsigned short* yb   = (unsigned short*)(ws + OFF_YB);
    unsigned short* wob  = (unsigned short*)(ws + OFF_WOB);

    // 0. convert weights to bf16 (re-done every launch; ws is re-poisoned)
    k_cvt_w<<<256, 256, 0, stream>>>(in_w, w_bf, 65536);
    k_cvt_w<<<128, 256, 0, stream>>>(out_w, wob, 32768);
    // 1. LN + in_proj (bf16 MFMA)
    k_ln_inproj_mfma<<<512, 256, 0, stream>>>(x, ln_g, ln_b, w_bf, xz);
    // forward branch: fused conv+xproj+dtproj, then scan -> yf (bf16)
    k_cxdt<<<512, 256, 0, stream>>>(xz, conv_w, conv_b, xproj_w, dtp_w, dtp_b,
                                    xc, dl, bc, 0);
    k_scan<<<256, 256, 0, stream>>>(dl, xc, bc, xz, A_log, D_f, yf, 0);
    // backward branch -> yb (bf16)
    k_cxdt<<<512, 256, 0, stream>>>(xz, conv_w_b, conv_b_b, xproj_wb, dtp_w_b, dtp_b_b,
                                    xc, dl, bc, 1);
    k_scan<<<256, 256, 0, stream>>>(dl, xc, bc, xz, A_b_log, D_b, yb, 1);
    // out_proj (MFMA over yf+yb) + un-shuffle + residual
    k_outproj_mfma<<<128, 256, 0, stream>>>(yf, yb, wob, x, out);
}